// Round 4
// baseline (604.892 us; speedup 1.0000x reference)
//
#include <hip/hip_runtime.h>

// Correctly-rounded float decay constants
#define DEC1 0.36787944117144233f   // exp(-1)    : psp1 decay, layer1 refractory
#define DEC2 0.60653065971263342f   // exp(-1/2)  : psp2 decay, layer2 refractory
#define DEC3 0.77880078307140487f   // exp(-1/4)  : psp3 decay, layer3 refractory

typedef float v2f __attribute__((ext_vector_type(2)));

// ---------------------------------------------------------------------------
// Weight re-layout into d_ws:  w1r[c][ky][kx][o] (400 f)  w2r[c][ky][kx][o]
// (576 f)  wupr[o][di][dj][c] pre-flipped for conv_transpose (64 f).
// ---------------------------------------------------------------------------
__global__ void prep_weights(const float* __restrict__ w1,
                             const float* __restrict__ w2,
                             const float* __restrict__ wup,
                             float* __restrict__ wr)
{
    int i = blockIdx.x * 256 + threadIdx.x;
    if (i < 400) {
        int o = i & 7, tap = i >> 3;
        int c = tap / 25, rem = tap % 25, ky = rem / 5, kx = rem % 5;
        wr[i] = w1[((o * 2 + c) * 5 + ky) * 5 + kx];
    }
    if (i < 576) {
        int o = i & 7, tap = i >> 3;
        int c = tap / 9, rem = tap % 9, ky = rem / 3, kx = rem % 3;
        wr[400 + i] = w2[((o * 8 + c) * 3 + ky) * 3 + kx];
    }
    if (i < 64) {
        int c = i & 7, r = i >> 3;
        int dj = r & 1, di = (r >> 1) & 1, o = r >> 2;
        wr[976 + i] = wup[((o * 8 + c) * 2 + (1 - di)) * 2 + (1 - dj)];
    }
}

// spike + following psp, 4 consecutive timesteps (u = float4 over t)
static __device__ __forceinline__ float4 spike_psp4(float4 u, float th, float dref,
                                                    float dq, float& r, float& q)
{
    float4 qv; float v, s;
    v = __fadd_rn(u.x, r); s = (v >= th) ? 1.f : 0.f;
    r = __fsub_rn(__fmul_rn(dref, r), __fmul_rn(th, s));
    q = __fadd_rn(__fmul_rn(dq, q), s); qv.x = q;
    v = __fadd_rn(u.y, r); s = (v >= th) ? 1.f : 0.f;
    r = __fsub_rn(__fmul_rn(dref, r), __fmul_rn(th, s));
    q = __fadd_rn(__fmul_rn(dq, q), s); qv.y = q;
    v = __fadd_rn(u.z, r); s = (v >= th) ? 1.f : 0.f;
    r = __fsub_rn(__fmul_rn(dref, r), __fmul_rn(th, s));
    q = __fadd_rn(__fmul_rn(dq, q), s); qv.z = q;
    v = __fadd_rn(u.w, r); s = (v >= th) ? 1.f : 0.f;
    r = __fsub_rn(__fmul_rn(dref, r), __fmul_rn(th, s));
    q = __fadd_rn(__fmul_rn(dq, q), s); qv.w = q;
    return qv;
}

// final spike (emits hard spikes), 4 timesteps
static __device__ __forceinline__ float4 spike4(float4 u, float th, float dref, float& r)
{
    float4 ov; float v, s;
    v = __fadd_rn(u.x, r); s = (v >= th) ? 1.f : 0.f;
    r = __fsub_rn(__fmul_rn(dref, r), __fmul_rn(th, s)); ov.x = s;
    v = __fadd_rn(u.y, r); s = (v >= th) ? 1.f : 0.f;
    r = __fsub_rn(__fmul_rn(dref, r), __fmul_rn(th, s)); ov.y = s;
    v = __fadd_rn(u.z, r); s = (v >= th) ? 1.f : 0.f;
    r = __fsub_rn(__fmul_rn(dref, r), __fmul_rn(th, s)); ov.z = s;
    v = __fadd_rn(u.w, r); s = (v >= th) ? 1.f : 0.f;
    r = __fsub_rn(__fmul_rn(dref, r), __fmul_rn(th, s)); ov.w = s;
    return ov;
}

// packed fma: two independent t-elements per v_pk_fma_f32. Same IEEE fma
// rounding per element, same accumulation order -> bit-identical output.
#define PKFMA(ALO_, AHI_, WV_, DLO_, DHI_) { \
    v2f wv2_ = { (WV_), (WV_) }; \
    ALO_ = __builtin_elementwise_fma(wv2_, DLO_, ALO_); \
    AHI_ = __builtin_elementwise_fma(wv2_, DHI_, AHI_); }

// psp1 leaky-integrate 4 steps: state in `st`, input X_, write V_ out
#define PSP4(V_, X_, st) { \
    V_.x = __fadd_rn(__fmul_rn(DEC1, st),   X_.x); \
    V_.y = __fadd_rn(__fmul_rn(DEC1, V_.x), X_.y); \
    V_.z = __fadd_rn(__fmul_rn(DEC1, V_.y), X_.z); \
    V_.w = __fadd_rn(__fmul_rn(DEC1, V_.z), X_.w); st = V_.w; }

// ---------------------------------------------------------------------------
// R17 = R16 + explicit software pipeline in B-conv/C-conv: stage next
// (c,ky) row's taps into named registers BEFORE the current row's FMAs.
// Rationale: R16 proved traffic is latency-hidden (FETCH 135->84 MB, WRITE
// 276->221 MB, time flat 391->394) -> bottleneck is within-wave LDS latency
// exposed once per conv row (unroll-1 loops give the scheduler nothing to
// hoist; R14's full unroll failed via code bloat WITHOUT hoisting, VGPR
// stayed 88). Here the rolled body stays small; loads for row i+1 issue
// ~160 VALU cycles before their first use, so the compiler's counted
// lgkmcnt wait is already satisfied. FMA order per output unchanged ->
// bit-exact. Flattened row index with uniform-scalar (nc,nk) advance;
// last iteration redundantly reloads the final row (harmless, uniform).
// Tested-and-rejected departures (keep for the record):
//  - R3  finer tile / 4 blocks/CU: 3x LDS read amplification, regressed.
//  - R8  paired 64B stores: broke L2 dirty-line merging (+300 MB), regressed.
//  - R10 sP1 stride 17: conflicts are structural wave64-b128 cost, neutral.
//  - R12 wave-specialized P/Q (2 barriers): block phase drift halved L2 line
//    survival, regressed. 5-barrier lockstep keeps line reuse alive.
//  - R14 full conv unroll: +code bloat, +addr VALU, no read batching,
//    regressed 391->429 (rolled conv bodies are load-bearing).
//  - R15 C-conv och-merge to 128 thr: LDS conflicts -40% but stage C issue
//    width halved (2 SIMDs idle), regressed 391->420.
//  - R16 128B store buffering: traffic -3x, time neutral (kept: free
//    robustness; proves HBM is not the bottleneck).
// ---------------------------------------------------------------------------
__global__ __launch_bounds__(256, 2)
void snn_fused(const float* __restrict__ spk,
               const float* __restrict__ wr,
               float* __restrict__ out)
{
    const int tid  = threadIdx.x;
    const int b    = blockIdx.x >> 6;
    const int tile = blockIdx.x & 63;
    const int gy0  = (tile >> 3) << 3;
    const int gx0  = (tile & 7) << 3;

    __shared__ float4 sP1[2][2][2][224]; // [parity][ch][thalf][14 rows x 16]
    __shared__ float4 sP2[8][2][100];    // [ch][thalf][10x10 px] (acc then psp2)
    __shared__ float4 sP3[8][2][64];     // [ch][thalf][ 8x8 px]  (acc then psp3)

    // persistent per-thread recurrent state
    float aP0 = 0.f, aP1 = 0.f;
    float rB[4], qB[4];
    float rC[2] = {0.f, 0.f}, qC[2] = {0.f, 0.f};
    float r3[2] = {0.f, 0.f};
#pragma unroll
    for (int i = 0; i < 4; ++i) { rB[i] = 0.f; qB[i] = 0.f; }

    // ---- stage A: psp1 region 14x14, threads 0..195 ----
    const int ary = tid / 14, arx = tid % 14;
    const int aidx = ary * 16 + arx;           // padded row stride 16
    const int aiy = gy0 - 3 + ary, aix = gx0 - 3 + arx;
    const bool avalid = (tid < 196) && (aiy >= 0) && (aiy < 64) && (aix >= 0) && (aix < 64);
    const int aoff0 = avalid ? (((b * 2 + 0) * 64 + aiy) * 64 + aix) * 200 : 0;
    const int aoff1 = avalid ? (((b * 2 + 1) * 64 + aiy) * 64 + aix) * 200 : 0;

    // ---- stage B: thread = (bh = tid>>7, bpx = tid&127 < 100) ----
    const int bh   = __builtin_amdgcn_readfirstlane(tid >> 7);
    const int bpx  = tid & 127;
    int by_, bx_;
    if (bpx < 80) { by_ = bpx >> 3; bx_ = bpx & 7; }
    else          { int t2 = bpx - 80; by_ = t2 >> 1; bx_ = 8 + (t2 & 1); }
    const int by = by_, bx = bx_;
    const int bwr = by * 10 + bx;              // sP2 px index (bijective)
    const int ochB = tid >> 7;                 // B-rec state owner quad

    // ---- C-conv: thread = (ch2 = tid>>7 -> t-half, cop -> och quad, px) ----
    const int ch2  = __builtin_amdgcn_readfirstlane(tid >> 7);
    const int cop  = __builtin_amdgcn_readfirstlane(tid >> 6) & 1;
    const int cpx  = tid & 63;
    const int cy   = cpx >> 3, cx = cpx & 7;
    const int och2 = (tid >> 6) * 2;           // C-rec state owner pair

    // ---- stage D: thread = (od = t>>7, ddi = (t>>6)&1, px) ----
    const int od  = tid >> 7;
    const int ddi = (tid >> 6) & 1;
    const int dpx = tid & 63;
    const int dy  = dpx >> 3, dxx = dpx & 7;
    const int diy = gy0 + dy, dix = gx0 + dxx;

    // bilinear 2x upsample weights (jax.image.resize "linear")
    const float ay  = ddi ? ((diy == 63) ? 1.f : 0.75f) : ((diy == 0) ? 0.f : 0.25f);
    const float byw = ddi ? ((diy == 63) ? 0.f : 0.25f) : ((diy == 0) ? 1.f : 0.75f);
    const float ax0 = (dix == 0)  ? 0.f : 0.25f;   // dj = 0
    const float bx0 = (dix == 0)  ? 1.f : 0.75f;
    const float ax1 = (dix == 63) ? 1.f : 0.75f;   // dj = 1
    const float bx1 = (dix == 63) ? 0.f : 0.25f;
    const int   didx = (dy + 2 + ddi) * 16 + (dxx + 2);

    // out base offsets for this thread's two pixels (dj = 0, 1)
    const int opix0 = (((b * 2 + od) * 128 + (2 * diy + ddi)) * 128 + 2 * dix) * 200;
    const int opix1 = opix0 + 200;

    // output register buffer: 3 chunks x (2 dj x 2 h) float4, flushed with the
    // 4th chunk's values as one 128B run per pixel. Named regs, static access.
    float4 s0, s1, s2, s3, s4, s5, s6, s7, s8, s9, s10, s11;

    // ---- prefetch registers: chunk 0's input ----
    float4 x00 = make_float4(0.f,0.f,0.f,0.f), x01 = x00, x10 = x00, x11 = x00;
    if (avalid) {
        x00 = *(const float4*)(spk + aoff0);
        x01 = *(const float4*)(spk + aoff0 + 4);
        x10 = *(const float4*)(spk + aoff1);
        x11 = *(const float4*)(spk + aoff1 + 4);
    }

#pragma unroll 1
    for (int ck = 0; ck < 25; ++ck) {
        const int t0 = ck * 8;
        const int p  = ck & 1;

        // ================= stage A: psp1 + prefetch next chunk =============
        if (tid < 196) {
            float4 v;
            PSP4(v, x00, aP0); sP1[p][0][0][aidx] = v;
            PSP4(v, x01, aP0); sP1[p][0][1][aidx] = v;
            PSP4(v, x10, aP1); sP1[p][1][0][aidx] = v;
            PSP4(v, x11, aP1); sP1[p][1][1][aidx] = v;
            if (ck < 24 && avalid) {
                x00 = *(const float4*)(spk + aoff0 + t0 + 8);
                x01 = *(const float4*)(spk + aoff0 + t0 + 12);
                x10 = *(const float4*)(spk + aoff1 + t0 + 8);
                x11 = *(const float4*)(spk + aoff1 + t0 + 12);
            }
        }
        __syncthreads();   // b1: sP1[p] ready; prev-chunk C-conv done with sP2

        // ============ stage B-conv: conv1 5x5, all 8 och, one t-half =======
        // software-pipelined over 10 rows (c,ky): preload row i+1 while
        // FMAing row i. Accumulation order per output: c->ky->kx (unchanged).
        if (bpx < 100) {
            v2f alo[8], ahi[8];
#pragma unroll
            for (int o = 0; o < 8; ++o) { alo[o] = (v2f)(0.f); ahi[o] = (v2f)(0.f); }
            const float4* rp = &sP1[p][0][bh][by * 16 + bx];
            float4 d0 = rp[0], d1 = rp[1], d2 = rp[2], d3 = rp[3], d4 = rp[4];
            int nc = 0, nk = 1;           // row to preload this iter (= row i+1)
            const float* wrow = wr;
#pragma unroll 1
            for (int i = 0; i < 10; ++i) {
                const float4* rn = &sP1[p][nc][bh][(by + nk) * 16 + bx];
                float4 n0 = rn[0], n1 = rn[1], n2 = rn[2], n3 = rn[3], n4 = rn[4];
#pragma unroll
                for (int kx = 0; kx < 5; ++kx) {
                    float4 d = (kx == 0) ? d0 : (kx == 1) ? d1 : (kx == 2) ? d2
                             : (kx == 3) ? d3 : d4;
                    v2f dlo = { d.x, d.y }, dhi = { d.z, d.w };
#pragma unroll
                    for (int o = 0; o < 8; ++o) {
                        float wv = wrow[kx * 8 + o];
                        PKFMA(alo[o], ahi[o], wv, dlo, dhi);
                    }
                }
                wrow += 40;
                d0 = n0; d1 = n1; d2 = n2; d3 = n3; d4 = n4;
                ++nk;
                if (nk == 5) { nk = 0; ++nc; }
                if (nc == 2) { nc = 1; nk = 4; }   // clamp: last iter reloads row 9
            }
#pragma unroll
            for (int o = 0; o < 8; ++o)
                sP2[o][bh][bwr] = make_float4(alo[o].x, alo[o].y, ahi[o].x, ahi[o].y);
        }
        __syncthreads();   // b2: acc ready

        // ============ stage B-rec: spike1 + psp2 in-place on sP2 ===========
        if (bpx < 100) {
#pragma unroll
            for (int j = 0; j < 4; ++j) {
                const int o = ochB * 4 + j;
                float4 u0 = sP2[o][0][bwr];
                float4 u1 = sP2[o][1][bwr];
                float4 q0 = spike_psp4(u0, 30.f, DEC1, DEC2, rB[j], qB[j]);
                sP2[o][0][bwr] = q0;
                float4 q1 = spike_psp4(u1, 30.f, DEC1, DEC2, rB[j], qB[j]);
                sP2[o][1][bwr] = q1;
            }
        }
        __syncthreads();   // b3: psp2 ready

        // ============ stage C-conv: conv2 3x3, och quad, one t-half ========
        // software-pipelined over 24 rows (c,ky), same scheme as B-conv.
        {
            v2f alo[4], ahi[4];
#pragma unroll
            for (int j = 0; j < 4; ++j) { alo[j] = (v2f)(0.f); ahi[j] = (v2f)(0.f); }
            const float4* rp = &sP2[0][ch2][cy * 10 + cx];
            float4 d0 = rp[0], d1 = rp[1], d2 = rp[2];
            int nc = 0, nk = 1;
            const float* wrow = wr + 400 + cop * 4;
#pragma unroll 1
            for (int i = 0; i < 24; ++i) {
                const float4* rn = &sP2[nc][ch2][(cy + nk) * 10 + cx];
                float4 n0 = rn[0], n1 = rn[1], n2 = rn[2];
#pragma unroll
                for (int kx = 0; kx < 3; ++kx) {
                    float4 d = (kx == 0) ? d0 : (kx == 1) ? d1 : d2;
                    v2f dlo = { d.x, d.y }, dhi = { d.z, d.w };
#pragma unroll
                    for (int j = 0; j < 4; ++j) {
                        float wv = wrow[kx * 8 + j];
                        PKFMA(alo[j], ahi[j], wv, dlo, dhi);
                    }
                }
                wrow += 24;
                d0 = n0; d1 = n1; d2 = n2;
                ++nk;
                if (nk == 3) { nk = 0; ++nc; }
                if (nc == 8) { nc = 7; nk = 2; }   // clamp: last iter reloads row 23
            }
#pragma unroll
            for (int j = 0; j < 4; ++j)
                sP3[cop * 4 + j][ch2][cpx] =
                    make_float4(alo[j].x, alo[j].y, ahi[j].x, ahi[j].y);
        }
        __syncthreads();   // b4: acc ready

        // ============ stage C-rec: spike2 + psp3 in-place on sP3 ===========
        {
#pragma unroll
            for (int j = 0; j < 2; ++j) {
                const int o = och2 + j;
                float4 u0 = sP3[o][0][cpx];
                float4 u1 = sP3[o][1][cpx];
                float4 q0 = spike_psp4(u0, 50.f, DEC2, DEC3, rC[j], qC[j]);
                sP3[o][0][cpx] = q0;
                float4 q1 = spike_psp4(u1, 50.f, DEC2, DEC3, rC[j], qC[j]);
                sP3[o][1][cpx] = q1;
            }
        }
        __syncthreads();   // b5: psp3 ready

        // ============ stage D: convT 2x2 s2 + psp1 bilinear-up + spike3 ====
        {
            float4 ovv0, ovv1, ovv2, ovv3;   // (dj,h) outputs of this chunk
#pragma unroll 1
            for (int h = 0; h < 2; ++h) {
                float4 p3[8];
#pragma unroll
                for (int c = 0; c < 8; ++c) p3[c] = sP3[c][h][dpx];
                float4 P0a = sP1[p][od][h][didx];
                float4 P0b = sP1[p][od][h][didx + 1];
                float4 P0c = sP1[p][od][h][didx + 2];
                float4 P1a = sP1[p][od][h][didx + 16];
                float4 P1b = sP1[p][od][h][didx + 17];
                float4 P1c = sP1[p][od][h][didx + 18];
#pragma unroll
                for (int dj = 0; dj < 2; ++dj) {
                    const float ax  = dj ? ax1 : ax0;
                    const float bxw = dj ? bx1 : bx0;
                    v2f tlo = (v2f)(0.f), thi = (v2f)(0.f);
                    const float* wD = wr + 976 + ((od * 2 + ddi) * 2 + dj) * 8;
#pragma unroll
                    for (int c = 0; c < 8; ++c) {
                        float wv = wD[c];
                        v2f dlo = { p3[c].x, p3[c].y }, dhi = { p3[c].z, p3[c].w };
                        PKFMA(tlo, thi, wv, dlo, dhi);
                    }
                    float4 tv = make_float4(tlo.x, tlo.y, thi.x, thi.y);
                    float4 A  = dj ? P0b : P0a;
                    float4 Bv = dj ? P0c : P0b;
                    float4 Cv = dj ? P1b : P1a;
                    float4 Dv = dj ? P1c : P1b;
                    float4 up, u; float ra, rb;
                    ra = __fadd_rn(__fmul_rn(ay, A.x),  __fmul_rn(byw, Cv.x));
                    rb = __fadd_rn(__fmul_rn(ay, Bv.x), __fmul_rn(byw, Dv.x));
                    up.x = __fadd_rn(__fmul_rn(ax, ra), __fmul_rn(bxw, rb));
                    ra = __fadd_rn(__fmul_rn(ay, A.y),  __fmul_rn(byw, Cv.y));
                    rb = __fadd_rn(__fmul_rn(ay, Bv.y), __fmul_rn(byw, Dv.y));
                    up.y = __fadd_rn(__fmul_rn(ax, ra), __fmul_rn(bxw, rb));
                    ra = __fadd_rn(__fmul_rn(ay, A.z),  __fmul_rn(byw, Cv.z));
                    rb = __fadd_rn(__fmul_rn(ay, Bv.z), __fmul_rn(byw, Dv.z));
                    up.z = __fadd_rn(__fmul_rn(ax, ra), __fmul_rn(bxw, rb));
                    ra = __fadd_rn(__fmul_rn(ay, A.w),  __fmul_rn(byw, Cv.w));
                    rb = __fadd_rn(__fmul_rn(ay, Bv.w), __fmul_rn(byw, Dv.w));
                    up.w = __fadd_rn(__fmul_rn(ax, ra), __fmul_rn(bxw, rb));
                    u.x = __fadd_rn(tv.x, up.x);
                    u.y = __fadd_rn(tv.y, up.y);
                    u.z = __fadd_rn(tv.z, up.z);
                    u.w = __fadd_rn(tv.w, up.w);
                    float4 ov = spike4(u, 100.f, DEC3, r3[dj]);
                    if (h == 0) { if (dj == 0) ovv0 = ov; else ovv2 = ov; }
                    else        { if (dj == 0) ovv1 = ov; else ovv3 = ov; }
                }
            }
            // -------- phase-buffered 128B-run stores (uniform branches) ----
            if (ck == 24) {
                // tail t=192..199: 32B per pixel, direct
                float* p0t = out + opix0 + t0;
                float* p1t = out + opix1 + t0;
                *(float4*)(p0t)     = ovv0; *(float4*)(p0t + 4) = ovv1;
                *(float4*)(p1t)     = ovv2; *(float4*)(p1t + 4) = ovv3;
            } else {
                const int ph = ck & 3;
                if (ph == 0)      { s0 = ovv0; s1 = ovv1; s2  = ovv2; s3  = ovv3; }
                else if (ph == 1) { s4 = ovv0; s5 = ovv1; s6  = ovv2; s7  = ovv3; }
                else if (ph == 2) { s8 = ovv0; s9 = ovv1; s10 = ovv2; s11 = ovv3; }
                else {
                    // flush full 128B (32 t) per pixel, written exactly once
                    float* p0f = out + opix0 + (t0 - 24);
                    *(float4*)(p0f)      = s0;   *(float4*)(p0f + 4)  = s1;
                    *(float4*)(p0f + 8)  = s4;   *(float4*)(p0f + 12) = s5;
                    *(float4*)(p0f + 16) = s8;   *(float4*)(p0f + 20) = s9;
                    *(float4*)(p0f + 24) = ovv0; *(float4*)(p0f + 28) = ovv1;
                    float* p1f = out + opix1 + (t0 - 24);
                    *(float4*)(p1f)      = s2;   *(float4*)(p1f + 4)  = s3;
                    *(float4*)(p1f + 8)  = s6;   *(float4*)(p1f + 12) = s7;
                    *(float4*)(p1f + 16) = s10;  *(float4*)(p1f + 20) = s11;
                    *(float4*)(p1f + 24) = ovv2; *(float4*)(p1f + 28) = ovv3;
                }
            }
        }
        // no end barrier: next A writes sP1[p^1]; sP2 safe until next B-conv
        // (separated by b1'); sP3 safe until next C-conv (separated by b3').
    }
}

extern "C" void kernel_launch(void* const* d_in, const int* in_sizes, int n_in,
                              void* d_out, int out_size, void* d_ws, size_t ws_size,
                              hipStream_t stream)
{
    const float* spk = (const float*)d_in[0];
    const float* w1  = (const float*)d_in[1];
    const float* w2  = (const float*)d_in[2];
    const float* wup = (const float*)d_in[3];
    float* outp = (float*)d_out;
    float* wr   = (float*)d_ws;   // 1040 floats of re-laid-out weights

    prep_weights<<<dim3(3), dim3(256), 0, stream>>>(w1, w2, wup, wr);
    snn_fused<<<dim3(512), dim3(256), 0, stream>>>(spk, wr, outp);
}

// Round 5
// 577.042 us; speedup vs baseline: 1.0483x; 1.0483x over previous
//
#include <hip/hip_runtime.h>

// Correctly-rounded float decay constants
#define DEC1 0.36787944117144233f   // exp(-1)    : psp1 decay, layer1 refractory
#define DEC2 0.60653065971263342f   // exp(-1/2)  : psp2 decay, layer2 refractory
#define DEC3 0.77880078307140487f   // exp(-1/4)  : psp3 decay, layer3 refractory

typedef float v2f __attribute__((ext_vector_type(2)));

// ---------------------------------------------------------------------------
// Weight re-layout into d_ws:  w1r[c][ky][kx][o] (400 f)  w2r[c][ky][kx][o]
// (576 f)  wupr[o][di][dj][c] pre-flipped for conv_transpose (64 f).
// ---------------------------------------------------------------------------
__global__ void prep_weights(const float* __restrict__ w1,
                             const float* __restrict__ w2,
                             const float* __restrict__ wup,
                             float* __restrict__ wr)
{
    int i = blockIdx.x * 256 + threadIdx.x;
    if (i < 400) {
        int o = i & 7, tap = i >> 3;
        int c = tap / 25, rem = tap % 25, ky = rem / 5, kx = rem % 5;
        wr[i] = w1[((o * 2 + c) * 5 + ky) * 5 + kx];
    }
    if (i < 576) {
        int o = i & 7, tap = i >> 3;
        int c = tap / 9, rem = tap % 9, ky = rem / 3, kx = rem % 3;
        wr[400 + i] = w2[((o * 8 + c) * 3 + ky) * 3 + kx];
    }
    if (i < 64) {
        int c = i & 7, r = i >> 3;
        int dj = r & 1, di = (r >> 1) & 1, o = r >> 2;
        wr[976 + i] = wup[((o * 8 + c) * 2 + (1 - di)) * 2 + (1 - dj)];
    }
}

// spike + following psp, 4 consecutive timesteps (u = float4 over t)
static __device__ __forceinline__ float4 spike_psp4(float4 u, float th, float dref,
                                                    float dq, float& r, float& q)
{
    float4 qv; float v, s;
    v = __fadd_rn(u.x, r); s = (v >= th) ? 1.f : 0.f;
    r = __fsub_rn(__fmul_rn(dref, r), __fmul_rn(th, s));
    q = __fadd_rn(__fmul_rn(dq, q), s); qv.x = q;
    v = __fadd_rn(u.y, r); s = (v >= th) ? 1.f : 0.f;
    r = __fsub_rn(__fmul_rn(dref, r), __fmul_rn(th, s));
    q = __fadd_rn(__fmul_rn(dq, q), s); qv.y = q;
    v = __fadd_rn(u.z, r); s = (v >= th) ? 1.f : 0.f;
    r = __fsub_rn(__fmul_rn(dref, r), __fmul_rn(th, s));
    q = __fadd_rn(__fmul_rn(dq, q), s); qv.z = q;
    v = __fadd_rn(u.w, r); s = (v >= th) ? 1.f : 0.f;
    r = __fsub_rn(__fmul_rn(dref, r), __fmul_rn(th, s));
    q = __fadd_rn(__fmul_rn(dq, q), s); qv.w = q;
    return qv;
}

// final spike (emits hard spikes), 4 timesteps
static __device__ __forceinline__ float4 spike4(float4 u, float th, float dref, float& r)
{
    float4 ov; float v, s;
    v = __fadd_rn(u.x, r); s = (v >= th) ? 1.f : 0.f;
    r = __fsub_rn(__fmul_rn(dref, r), __fmul_rn(th, s)); ov.x = s;
    v = __fadd_rn(u.y, r); s = (v >= th) ? 1.f : 0.f;
    r = __fsub_rn(__fmul_rn(dref, r), __fmul_rn(th, s)); ov.y = s;
    v = __fadd_rn(u.z, r); s = (v >= th) ? 1.f : 0.f;
    r = __fsub_rn(__fmul_rn(dref, r), __fmul_rn(th, s)); ov.z = s;
    v = __fadd_rn(u.w, r); s = (v >= th) ? 1.f : 0.f;
    r = __fsub_rn(__fmul_rn(dref, r), __fmul_rn(th, s)); ov.w = s;
    return ov;
}

// packed fma: two independent t-elements per v_pk_fma_f32. Same IEEE fma
// rounding per element, same accumulation order -> bit-identical output.
#define PKQ(AL_, AH_, WV_, DLO_, DHI_) { \
    v2f wv2_ = { (WV_), (WV_) }; \
    AL_ = __builtin_elementwise_fma(wv2_, DLO_, AL_); \
    AH_ = __builtin_elementwise_fma(wv2_, DHI_, AH_); }

// psp1 leaky-integrate 4 steps: state in `st`, input X_, write V_ out
#define PSP4(V_, X_, st) { \
    V_.x = __fadd_rn(__fmul_rn(DEC1, st),   X_.x); \
    V_.y = __fadd_rn(__fmul_rn(DEC1, V_.x), X_.y); \
    V_.z = __fadd_rn(__fmul_rn(DEC1, V_.y), X_.z); \
    V_.w = __fadd_rn(__fmul_rn(DEC1, V_.z), X_.w); st = V_.w; }

// ---- B-conv row FMA: 5 kx taps x 8 och, och packed in weight float4 pairs.
// Accumulation order per output och: kx ascending (rows outer) == original.
#define BTAP(D_, WA_, WB_) { v2f dlo_ = { D_.x, D_.y }, dhi_ = { D_.z, D_.w }; \
    PKQ(alo[0], ahi[0], WA_.x, dlo_, dhi_); PKQ(alo[1], ahi[1], WA_.y, dlo_, dhi_); \
    PKQ(alo[2], ahi[2], WA_.z, dlo_, dhi_); PKQ(alo[3], ahi[3], WA_.w, dlo_, dhi_); \
    PKQ(alo[4], ahi[4], WB_.x, dlo_, dhi_); PKQ(alo[5], ahi[5], WB_.y, dlo_, dhi_); \
    PKQ(alo[6], ahi[6], WB_.z, dlo_, dhi_); PKQ(alo[7], ahi[7], WB_.w, dlo_, dhi_); }
#define BROWF(S) { BTAP(S##d0, S##w0, S##w1) BTAP(S##d1, S##w2, S##w3) \
    BTAP(S##d2, S##w4, S##w5) BTAP(S##d3, S##w6, S##w7) BTAP(S##d4, S##w8, S##w9) }
// preload one B row (weights then data, all DS -> in-order), advance + clamp
#define BPRE(S) { \
    const float4* rn_ = &sP1[p][nc][bh][(by + nk) * 16 + bx]; \
    const float4* wq_ = sW4 + wrow; \
    S##w0 = wq_[0]; S##w1 = wq_[1]; S##w2 = wq_[2]; S##w3 = wq_[3]; \
    S##w4 = wq_[4]; S##w5 = wq_[5]; S##w6 = wq_[6]; S##w7 = wq_[7]; \
    S##w8 = wq_[8]; S##w9 = wq_[9]; \
    S##d0 = rn_[0]; S##d1 = rn_[1]; S##d2 = rn_[2]; S##d3 = rn_[3]; S##d4 = rn_[4]; \
    ++nk; if (nk == 5) { nk = 0; ++nc; } if (nc == 2) { nc = 1; nk = 4; } \
    wrow += 10; if (wrow == 100) wrow = 90; }

// ---- C-conv row FMA: 3 kx taps x 4 och (cop quad)
#define CTAP(D_, WA_) { v2f dlo_ = { D_.x, D_.y }, dhi_ = { D_.z, D_.w }; \
    PKQ(clo[0], chi[0], WA_.x, dlo_, dhi_); PKQ(clo[1], chi[1], WA_.y, dlo_, dhi_); \
    PKQ(clo[2], chi[2], WA_.z, dlo_, dhi_); PKQ(clo[3], chi[3], WA_.w, dlo_, dhi_); }
#define CROWF(S) { CTAP(S##d0, S##w0) CTAP(S##d1, S##w1) CTAP(S##d2, S##w2) }
#define CPRE(S) { \
    const float4* rn_ = &sP2[nc2][ch2][(cy + nk2) * 10 + cx]; \
    const float4* wq_ = sW4 + wrow2; \
    S##w0 = wq_[cop]; S##w1 = wq_[2 + cop]; S##w2 = wq_[4 + cop]; \
    S##d0 = rn_[0]; S##d1 = rn_[1]; S##d2 = rn_[2]; \
    ++nk2; if (nk2 == 3) { nk2 = 0; ++nc2; } if (nc2 == 8) { nc2 = 7; nk2 = 2; } \
    wrow2 += 6; if (wrow2 == 244) wrow2 = 238; }

// ---------------------------------------------------------------------------
// R18 = R13 skeleton + LDS-resident weights + true 2-row ping-pong software
// pipeline in B-conv/C-conv (pure-DS inner loops).
// Root cause found (explains R14 AND R17 failures): conv weights were
// wave-uniform GLOBAL loads -> hipcc emits s_load inside each row iteration;
// SMEM shares lgkmcnt with DS but completes out-of-order vs DS, so the
// compiler must emit lgkmcnt(0) FULL DRAINS every row. No data-side
// scheduling could ever pipeline across those. Fix: stage all 1040 weights
// into LDS once (+4.2KB, still 2 blocks/CU); weight reads become broadcast
// ds_read_b128 (uniform addr, conflict-free); rows double-buffered in named
// registers (2 rows/iter ping-pong, no rotation moves); sched_barrier(0)
// pins preloads above FMAs. DS is in-order -> counted lgkmcnt waits, already
// satisfied (issued one full row = ~320 VALU cycles earlier). R16's store
// buffer reverted to fund the pipeline registers (was time-neutral; WRITE
// returns to ~275MB which R16 proved is fully latency-hidden).
// FMA order per output unchanged everywhere -> bit-exact.
// Tested-and-rejected (record): R3 finer tile; R8 64B store pairs; R10
// stride-17; R12 2-barrier wave-spec; R14 full unroll; R15 och-merge;
// R16 128B store buffer (neutral); R17 data-only pipeline (defeated by
// the SMEM drains above).
// ---------------------------------------------------------------------------
__global__ __launch_bounds__(256, 2)
void snn_fused(const float* __restrict__ spk,
               const float* __restrict__ wr,
               float* __restrict__ out)
{
    const int tid  = threadIdx.x;
    const int b    = blockIdx.x >> 6;
    const int tile = blockIdx.x & 63;
    const int gy0  = (tile >> 3) << 3;
    const int gx0  = (tile & 7) << 3;

    __shared__ float4 sP1[2][2][2][224]; // [parity][ch][thalf][14 rows x 16]
    __shared__ float4 sP2[8][2][100];    // [ch][thalf][10x10 px] (acc then psp2)
    __shared__ float4 sP3[8][2][64];     // [ch][thalf][ 8x8 px]  (acc then psp3)
    __shared__ float4 sW4[264];          // re-laid-out weights (1040 f + pad)

    // stage weights global -> LDS once (b1 of chunk 0 orders vs first use)
    for (int i = tid; i < 260; i += 256) sW4[i] = ((const float4*)wr)[i];

    // persistent per-thread recurrent state
    float aP0 = 0.f, aP1 = 0.f;
    float rB[4], qB[4];
    float rC[2] = {0.f, 0.f}, qC[2] = {0.f, 0.f};
    float r3[2] = {0.f, 0.f};
#pragma unroll
    for (int i = 0; i < 4; ++i) { rB[i] = 0.f; qB[i] = 0.f; }

    // ---- stage A: psp1 region 14x14, threads 0..195 ----
    const int ary = tid / 14, arx = tid % 14;
    const int aidx = ary * 16 + arx;           // padded row stride 16
    const int aiy = gy0 - 3 + ary, aix = gx0 - 3 + arx;
    const bool avalid = (tid < 196) && (aiy >= 0) && (aiy < 64) && (aix >= 0) && (aix < 64);
    const int aoff0 = avalid ? (((b * 2 + 0) * 64 + aiy) * 64 + aix) * 200 : 0;
    const int aoff1 = avalid ? (((b * 2 + 1) * 64 + aiy) * 64 + aix) * 200 : 0;

    // ---- stage B: thread = (bh = tid>>7, bpx = tid&127 < 100) ----
    const int bh   = __builtin_amdgcn_readfirstlane(tid >> 7);
    const int bpx  = tid & 127;
    int by_, bx_;
    if (bpx < 80) { by_ = bpx >> 3; bx_ = bpx & 7; }
    else          { int t2 = bpx - 80; by_ = t2 >> 1; bx_ = 8 + (t2 & 1); }
    const int by = by_, bx = bx_;
    const int bwr = by * 10 + bx;              // sP2 px index (bijective)
    const int ochB = tid >> 7;                 // B-rec state owner quad

    // ---- C-conv: thread = (ch2 = tid>>7 -> t-half, cop -> och quad, px) ----
    const int ch2  = __builtin_amdgcn_readfirstlane(tid >> 7);
    const int cop  = __builtin_amdgcn_readfirstlane(tid >> 6) & 1;
    const int cpx  = tid & 63;
    const int cy   = cpx >> 3, cx = cpx & 7;
    const int och2 = (tid >> 6) * 2;           // C-rec state owner pair

    // ---- stage D: thread = (od = t>>7, ddi = (t>>6)&1, px) ----
    const int od  = tid >> 7;
    const int ddi = (tid >> 6) & 1;
    const int dpx = tid & 63;
    const int dy  = dpx >> 3, dxx = dpx & 7;
    const int diy = gy0 + dy, dix = gx0 + dxx;

    // bilinear 2x upsample weights (jax.image.resize "linear")
    const float ay  = ddi ? ((diy == 63) ? 1.f : 0.75f) : ((diy == 0) ? 0.f : 0.25f);
    const float byw = ddi ? ((diy == 63) ? 0.f : 0.25f) : ((diy == 0) ? 1.f : 0.75f);
    const float ax0 = (dix == 0)  ? 0.f : 0.25f;   // dj = 0
    const float bx0 = (dix == 0)  ? 1.f : 0.75f;
    const float ax1 = (dix == 63) ? 1.f : 0.75f;   // dj = 1
    const float bx1 = (dix == 63) ? 0.f : 0.25f;
    const int   didx = (dy + 2 + ddi) * 16 + (dxx + 2);

    // out base offsets for this thread's two pixels (dj = 0, 1)
    const int opix0 = (((b * 2 + od) * 128 + (2 * diy + ddi)) * 128 + 2 * dix) * 200;
    const int opix1 = opix0 + 200;
    const int kD    = (od * 2 + ddi) * 2;      // convT weight row pair base

    // ---- prefetch registers: chunk 0's input ----
    float4 x00 = make_float4(0.f,0.f,0.f,0.f), x01 = x00, x10 = x00, x11 = x00;
    if (avalid) {
        x00 = *(const float4*)(spk + aoff0);
        x01 = *(const float4*)(spk + aoff0 + 4);
        x10 = *(const float4*)(spk + aoff1);
        x11 = *(const float4*)(spk + aoff1 + 4);
    }

#pragma unroll 1
    for (int ck = 0; ck < 25; ++ck) {
        const int t0 = ck * 8;
        const int p  = ck & 1;

        // ================= stage A: psp1 + prefetch next chunk =============
        if (tid < 196) {
            float4 v;
            PSP4(v, x00, aP0); sP1[p][0][0][aidx] = v;
            PSP4(v, x01, aP0); sP1[p][0][1][aidx] = v;
            PSP4(v, x10, aP1); sP1[p][1][0][aidx] = v;
            PSP4(v, x11, aP1); sP1[p][1][1][aidx] = v;
            if (ck < 24 && avalid) {
                x00 = *(const float4*)(spk + aoff0 + t0 + 8);
                x01 = *(const float4*)(spk + aoff0 + t0 + 12);
                x10 = *(const float4*)(spk + aoff1 + t0 + 8);
                x11 = *(const float4*)(spk + aoff1 + t0 + 12);
            }
        }
        __syncthreads();   // b1: sP1[p] ready; prev-chunk C-conv done with sP2

        // ============ stage B-conv: conv1 5x5, all 8 och, one t-half =======
        // 10 (c,ky) rows, ping-pong double-buffered (weights + data one full
        // row ahead, pure DS). Acc order per output: c->ky->kx (unchanged).
        if (bpx < 100) {
            v2f alo[8], ahi[8];
#pragma unroll
            for (int o = 0; o < 8; ++o) { alo[o] = (v2f)(0.f); ahi[o] = (v2f)(0.f); }
            float4 Ad0, Ad1, Ad2, Ad3, Ad4;
            float4 Aw0, Aw1, Aw2, Aw3, Aw4, Aw5, Aw6, Aw7, Aw8, Aw9;
            float4 Bd0, Bd1, Bd2, Bd3, Bd4;
            float4 Bw0, Bw1, Bw2, Bw3, Bw4, Bw5, Bw6, Bw7, Bw8, Bw9;
            int nc = 0, nk = 0, wrow = 0;
            BPRE(A)                       // row 0
#pragma unroll 1
            for (int i = 0; i < 5; ++i) {
                BPRE(B)                   // row 2i+1 (last iter: redundant 9)
                __builtin_amdgcn_sched_barrier(0);
                BROWF(A)                  // row 2i
                BPRE(A)                   // row 2i+2 (clamped)
                __builtin_amdgcn_sched_barrier(0);
                BROWF(B)                  // row 2i+1
            }
#pragma unroll
            for (int o = 0; o < 8; ++o)
                sP2[o][bh][bwr] = make_float4(alo[o].x, alo[o].y, ahi[o].x, ahi[o].y);
        }
        __syncthreads();   // b2: acc ready

        // ============ stage B-rec: spike1 + psp2 in-place on sP2 ===========
        if (bpx < 100) {
#pragma unroll
            for (int j = 0; j < 4; ++j) {
                const int o = ochB * 4 + j;
                float4 u0 = sP2[o][0][bwr];
                float4 u1 = sP2[o][1][bwr];
                float4 q0 = spike_psp4(u0, 30.f, DEC1, DEC2, rB[j], qB[j]);
                sP2[o][0][bwr] = q0;
                float4 q1 = spike_psp4(u1, 30.f, DEC1, DEC2, rB[j], qB[j]);
                sP2[o][1][bwr] = q1;
            }
        }
        __syncthreads();   // b3: psp2 ready

        // ============ stage C-conv: conv2 3x3, och quad, one t-half ========
        // 24 (c,ky) rows, same ping-pong pipeline, pure DS.
        {
            v2f clo[4], chi[4];
#pragma unroll
            for (int j = 0; j < 4; ++j) { clo[j] = (v2f)(0.f); chi[j] = (v2f)(0.f); }
            float4 Ed0, Ed1, Ed2, Ew0, Ew1, Ew2;
            float4 Fd0, Fd1, Fd2, Fw0, Fw1, Fw2;
            int nc2 = 0, nk2 = 0, wrow2 = 100;
            CPRE(E)                       // row 0
#pragma unroll 1
            for (int i = 0; i < 12; ++i) {
                CPRE(F)                   // row 2i+1 (last iter: redundant 23)
                __builtin_amdgcn_sched_barrier(0);
                CROWF(E)                  // row 2i
                CPRE(E)                   // row 2i+2 (clamped)
                __builtin_amdgcn_sched_barrier(0);
                CROWF(F)                  // row 2i+1
            }
#pragma unroll
            for (int j = 0; j < 4; ++j)
                sP3[cop * 4 + j][ch2][cpx] =
                    make_float4(clo[j].x, clo[j].y, chi[j].x, chi[j].y);
        }
        __syncthreads();   // b4: acc ready

        // ============ stage C-rec: spike2 + psp3 in-place on sP3 ===========
        {
#pragma unroll
            for (int j = 0; j < 2; ++j) {
                const int o = och2 + j;
                float4 u0 = sP3[o][0][cpx];
                float4 u1 = sP3[o][1][cpx];
                float4 q0 = spike_psp4(u0, 50.f, DEC2, DEC3, rC[j], qC[j]);
                sP3[o][0][cpx] = q0;
                float4 q1 = spike_psp4(u1, 50.f, DEC2, DEC3, rC[j], qC[j]);
                sP3[o][1][cpx] = q1;
            }
        }
        __syncthreads();   // b5: psp3 ready

        // ============ stage D: convT 2x2 s2 + psp1 bilinear-up + spike3 ====
        {
            // convT weights from LDS (broadcast), issued before the per-lane
            // reads below; DS in-order -> wait for p3 implies weights done.
            const float4 wd0a = sW4[244 + kD * 2 + 0], wd0b = sW4[244 + kD * 2 + 1];
            const float4 wd1a = sW4[244 + kD * 2 + 2], wd1b = sW4[244 + kD * 2 + 3];
#pragma unroll 1
            for (int h = 0; h < 2; ++h) {
                float4 p3[8];
#pragma unroll
                for (int c = 0; c < 8; ++c) p3[c] = sP3[c][h][dpx];
                float4 P0a = sP1[p][od][h][didx];
                float4 P0b = sP1[p][od][h][didx + 1];
                float4 P0c = sP1[p][od][h][didx + 2];
                float4 P1a = sP1[p][od][h][didx + 16];
                float4 P1b = sP1[p][od][h][didx + 17];
                float4 P1c = sP1[p][od][h][didx + 18];
#pragma unroll
                for (int dj = 0; dj < 2; ++dj) {
                    const float ax  = dj ? ax1 : ax0;
                    const float bxw = dj ? bx1 : bx0;
                    const float4 wA = dj ? wd1a : wd0a;
                    const float4 wB = dj ? wd1b : wd0b;
                    v2f tlo = (v2f)(0.f), thi = (v2f)(0.f);
                    { v2f dlo = { p3[0].x, p3[0].y }, dhi = { p3[0].z, p3[0].w };
                      PKQ(tlo, thi, wA.x, dlo, dhi); }
                    { v2f dlo = { p3[1].x, p3[1].y }, dhi = { p3[1].z, p3[1].w };
                      PKQ(tlo, thi, wA.y, dlo, dhi); }
                    { v2f dlo = { p3[2].x, p3[2].y }, dhi = { p3[2].z, p3[2].w };
                      PKQ(tlo, thi, wA.z, dlo, dhi); }
                    { v2f dlo = { p3[3].x, p3[3].y }, dhi = { p3[3].z, p3[3].w };
                      PKQ(tlo, thi, wA.w, dlo, dhi); }
                    { v2f dlo = { p3[4].x, p3[4].y }, dhi = { p3[4].z, p3[4].w };
                      PKQ(tlo, thi, wB.x, dlo, dhi); }
                    { v2f dlo = { p3[5].x, p3[5].y }, dhi = { p3[5].z, p3[5].w };
                      PKQ(tlo, thi, wB.y, dlo, dhi); }
                    { v2f dlo = { p3[6].x, p3[6].y }, dhi = { p3[6].z, p3[6].w };
                      PKQ(tlo, thi, wB.z, dlo, dhi); }
                    { v2f dlo = { p3[7].x, p3[7].y }, dhi = { p3[7].z, p3[7].w };
                      PKQ(tlo, thi, wB.w, dlo, dhi); }
                    float4 tv = make_float4(tlo.x, tlo.y, thi.x, thi.y);
                    float4 A  = dj ? P0b : P0a;
                    float4 Bv = dj ? P0c : P0b;
                    float4 Cv = dj ? P1b : P1a;
                    float4 Dv = dj ? P1c : P1b;
                    float4 up, u; float ra, rb;
                    ra = __fadd_rn(__fmul_rn(ay, A.x),  __fmul_rn(byw, Cv.x));
                    rb = __fadd_rn(__fmul_rn(ay, Bv.x), __fmul_rn(byw, Dv.x));
                    up.x = __fadd_rn(__fmul_rn(ax, ra), __fmul_rn(bxw, rb));
                    ra = __fadd_rn(__fmul_rn(ay, A.y),  __fmul_rn(byw, Cv.y));
                    rb = __fadd_rn(__fmul_rn(ay, Bv.y), __fmul_rn(byw, Dv.y));
                    up.y = __fadd_rn(__fmul_rn(ax, ra), __fmul_rn(bxw, rb));
                    ra = __fadd_rn(__fmul_rn(ay, A.z),  __fmul_rn(byw, Cv.z));
                    rb = __fadd_rn(__fmul_rn(ay, Bv.z), __fmul_rn(byw, Dv.z));
                    up.z = __fadd_rn(__fmul_rn(ax, ra), __fmul_rn(bxw, rb));
                    ra = __fadd_rn(__fmul_rn(ay, A.w),  __fmul_rn(byw, Cv.w));
                    rb = __fadd_rn(__fmul_rn(ay, Bv.w), __fmul_rn(byw, Dv.w));
                    up.w = __fadd_rn(__fmul_rn(ax, ra), __fmul_rn(bxw, rb));
                    u.x = __fadd_rn(tv.x, up.x);
                    u.y = __fadd_rn(tv.y, up.y);
                    u.z = __fadd_rn(tv.z, up.z);
                    u.w = __fadd_rn(tv.w, up.w);
                    float4 ov = spike4(u, 100.f, DEC3, r3[dj]);
                    float* op = out + (dj ? opix1 : opix0) + t0 + h * 4;
                    *(float4*)op = ov;
                }
            }
        }
        // no end barrier: next A writes sP1[p^1]; sP2 safe until next B-conv
        // (separated by b1'); sP3 safe until next C-conv (separated by b3').
    }
}

extern "C" void kernel_launch(void* const* d_in, const int* in_sizes, int n_in,
                              void* d_out, int out_size, void* d_ws, size_t ws_size,
                              hipStream_t stream)
{
    const float* spk = (const float*)d_in[0];
    const float* w1  = (const float*)d_in[1];
    const float* w2  = (const float*)d_in[2];
    const float* wup = (const float*)d_in[3];
    float* outp = (float*)d_out;
    float* wr   = (float*)d_ws;   // 1040 floats of re-laid-out weights

    prep_weights<<<dim3(3), dim3(256), 0, stream>>>(w1, w2, wup, wr);
    snn_fused<<<dim3(512), dim3(256), 0, stream>>>(spk, wr, outp);
}

// Round 6
// 567.340 us; speedup vs baseline: 1.0662x; 1.0171x over previous
//
#include <hip/hip_runtime.h>

// Correctly-rounded float decay constants
#define DEC1 0.36787944117144233f   // exp(-1)    : psp1 decay, layer1 refractory
#define DEC2 0.60653065971263342f   // exp(-1/2)  : psp2 decay, layer2 refractory
#define DEC3 0.77880078307140487f   // exp(-1/4)  : psp3 decay, layer3 refractory

typedef float v2f __attribute__((ext_vector_type(2)));

// ---------------------------------------------------------------------------
// Weight re-layout into d_ws:  w1r[c][ky][kx][o] (400 f)  w2r[c][ky][kx][o]
// (576 f)  wupr[o][di][dj][c] pre-flipped for conv_transpose (64 f).
// ---------------------------------------------------------------------------
__global__ void prep_weights(const float* __restrict__ w1,
                             const float* __restrict__ w2,
                             const float* __restrict__ wup,
                             float* __restrict__ wr)
{
    int i = blockIdx.x * 256 + threadIdx.x;
    if (i < 400) {
        int o = i & 7, tap = i >> 3;
        int c = tap / 25, rem = tap % 25, ky = rem / 5, kx = rem % 5;
        wr[i] = w1[((o * 2 + c) * 5 + ky) * 5 + kx];
    }
    if (i < 576) {
        int o = i & 7, tap = i >> 3;
        int c = tap / 9, rem = tap % 9, ky = rem / 3, kx = rem % 3;
        wr[400 + i] = w2[((o * 8 + c) * 3 + ky) * 3 + kx];
    }
    if (i < 64) {
        int c = i & 7, r = i >> 3;
        int dj = r & 1, di = (r >> 1) & 1, o = r >> 2;
        wr[976 + i] = wup[((o * 8 + c) * 2 + (1 - di)) * 2 + (1 - dj)];
    }
}

// spike + following psp, 4 consecutive timesteps (u = float4 over t)
static __device__ __forceinline__ float4 spike_psp4(float4 u, float th, float dref,
                                                    float dq, float& r, float& q)
{
    float4 qv; float v, s;
    v = __fadd_rn(u.x, r); s = (v >= th) ? 1.f : 0.f;
    r = __fsub_rn(__fmul_rn(dref, r), __fmul_rn(th, s));
    q = __fadd_rn(__fmul_rn(dq, q), s); qv.x = q;
    v = __fadd_rn(u.y, r); s = (v >= th) ? 1.f : 0.f;
    r = __fsub_rn(__fmul_rn(dref, r), __fmul_rn(th, s));
    q = __fadd_rn(__fmul_rn(dq, q), s); qv.y = q;
    v = __fadd_rn(u.z, r); s = (v >= th) ? 1.f : 0.f;
    r = __fsub_rn(__fmul_rn(dref, r), __fmul_rn(th, s));
    q = __fadd_rn(__fmul_rn(dq, q), s); qv.z = q;
    v = __fadd_rn(u.w, r); s = (v >= th) ? 1.f : 0.f;
    r = __fsub_rn(__fmul_rn(dref, r), __fmul_rn(th, s));
    q = __fadd_rn(__fmul_rn(dq, q), s); qv.w = q;
    return qv;
}

// final spike (emits hard spikes), 4 timesteps
static __device__ __forceinline__ float4 spike4(float4 u, float th, float dref, float& r)
{
    float4 ov; float v, s;
    v = __fadd_rn(u.x, r); s = (v >= th) ? 1.f : 0.f;
    r = __fsub_rn(__fmul_rn(dref, r), __fmul_rn(th, s)); ov.x = s;
    v = __fadd_rn(u.y, r); s = (v >= th) ? 1.f : 0.f;
    r = __fsub_rn(__fmul_rn(dref, r), __fmul_rn(th, s)); ov.y = s;
    v = __fadd_rn(u.z, r); s = (v >= th) ? 1.f : 0.f;
    r = __fsub_rn(__fmul_rn(dref, r), __fmul_rn(th, s)); ov.z = s;
    v = __fadd_rn(u.w, r); s = (v >= th) ? 1.f : 0.f;
    r = __fsub_rn(__fmul_rn(dref, r), __fmul_rn(th, s)); ov.w = s;
    return ov;
}

// packed fma: two independent t-elements per v_pk_fma_f32. Same IEEE fma
// rounding per element, same accumulation order -> bit-identical output.
#define PKFMA(ALO_, AHI_, WV_, DLO_, DHI_) { \
    v2f wv2_ = { (WV_), (WV_) }; \
    ALO_ = __builtin_elementwise_fma(wv2_, DLO_, ALO_); \
    AHI_ = __builtin_elementwise_fma(wv2_, DHI_, AHI_); }

// psp1 leaky-integrate 4 steps: state in `st`, input X_, write V_ out
#define PSP4(V_, X_, st) { \
    V_.x = __fadd_rn(__fmul_rn(DEC1, st),   X_.x); \
    V_.y = __fadd_rn(__fmul_rn(DEC1, V_.x), X_.y); \
    V_.z = __fadd_rn(__fmul_rn(DEC1, V_.y), X_.z); \
    V_.w = __fadd_rn(__fmul_rn(DEC1, V_.z), X_.w); st = V_.w; }

// ---------------------------------------------------------------------------
// R19 = terminal revert to R13 (best harness-verified: 569.6/570.8 us,
// 391 us steady). Final kernel of this session unless the confirm run
// surprises.
// Plateau evidence (structural, not a pipe roofline): VALU ~47%, LDS pipe
// ~55-60%, HBM 13%, OccupancyPercent ~21 (2 blocks/CU, grid-capped at 512 =
// 8 batch x 64 tiles). The floor is barrier-coupled latency: 5 barriers x
// 25 chunks with only cross-block drift for hiding. Everything tested
// against it, with the measured reason it failed:
//  - R3  finer tile / 4 blocks/CU: 3x LDS read amplification, regressed.
//  - R8  paired 64B stores: broke L2 dirty-line merging (+300 MB), regressed.
//  - R10 sP1 stride 17: conflicts are structural wave64-b128 cost, neutral.
//  - R12 wave-specialized P/Q (2 barriers): block phase drift halved L2 line
//    survival (FETCH 135->270 MB), regressed.
//  - R14 full conv unroll: +issue work, no read batching (VGPR stayed 88),
//    391->429.
//  - R15 C-conv och-merge: LDS conflicts -40% as predicted, but stage-C
//    issue width halved (2 SIMDs idle at b4), 391->420.
//  - R16 128B-run store buffering: WRITE 276->221 MB, FETCH 135->84 MB,
//    time NEUTRAL (394) -> all remaining traffic is latency-hidden.
//  - R17 data-side row pipeline: compiler re-sank preloads (VGPR 124->116),
//    neutral-regress (405).
//  - R18 LDS-resident weights + pure-DS ping-pong pipeline + sched_barrier:
//    compiler sank preloads again (VGPR 116), +DS weight reads, 413-441.
// What would have to change for more: >2 blocks/CU (impossible: grid is
// problem-fixed; finer tiles amplify LDS 3x), fewer barriers (breaks L2
// line survival), or compiler-level control of load placement that hipcc
// does not honor at source level (R14/R17/R18). Estimated pure-issue bound
// ~2x away but unreachable in this design space.
// ---------------------------------------------------------------------------
__global__ __launch_bounds__(256, 2)
void snn_fused(const float* __restrict__ spk,
               const float* __restrict__ wr,
               float* __restrict__ out)
{
    const int tid  = threadIdx.x;
    const int b    = blockIdx.x >> 6;
    const int tile = blockIdx.x & 63;
    const int gy0  = (tile >> 3) << 3;
    const int gx0  = (tile & 7) << 3;

    __shared__ float4 sP1[2][2][2][224]; // [parity][ch][thalf][14 rows x 16]
    __shared__ float4 sP2[8][2][100];    // [ch][thalf][10x10 px] (acc then psp2)
    __shared__ float4 sP3[8][2][64];     // [ch][thalf][ 8x8 px]  (acc then psp3)

    // persistent per-thread recurrent state
    float aP0 = 0.f, aP1 = 0.f;
    float rB[4], qB[4];
    float rC[2] = {0.f, 0.f}, qC[2] = {0.f, 0.f};
    float r3[2] = {0.f, 0.f};
#pragma unroll
    for (int i = 0; i < 4; ++i) { rB[i] = 0.f; qB[i] = 0.f; }

    // ---- stage A: psp1 region 14x14, threads 0..195 ----
    const int ary = tid / 14, arx = tid % 14;
    const int aidx = ary * 16 + arx;           // padded row stride 16
    const int aiy = gy0 - 3 + ary, aix = gx0 - 3 + arx;
    const bool avalid = (tid < 196) && (aiy >= 0) && (aiy < 64) && (aix >= 0) && (aix < 64);
    const int aoff0 = avalid ? (((b * 2 + 0) * 64 + aiy) * 64 + aix) * 200 : 0;
    const int aoff1 = avalid ? (((b * 2 + 1) * 64 + aiy) * 64 + aix) * 200 : 0;

    // ---- stage B: thread = (bh = tid>>7, bpx = tid&127 < 100) ----
    const int bh   = __builtin_amdgcn_readfirstlane(tid >> 7);
    const int bpx  = tid & 127;
    int by_, bx_;
    if (bpx < 80) { by_ = bpx >> 3; bx_ = bpx & 7; }
    else          { int t2 = bpx - 80; by_ = t2 >> 1; bx_ = 8 + (t2 & 1); }
    const int by = by_, bx = bx_;
    const int bwr = by * 10 + bx;              // sP2 px index (bijective)
    const int ochB = tid >> 7;                 // B-rec state owner quad

    // ---- C-conv: thread = (ch2 = tid>>7 -> t-half, cop -> och quad, px) ----
    const int ch2  = __builtin_amdgcn_readfirstlane(tid >> 7);
    const int cop  = __builtin_amdgcn_readfirstlane(tid >> 6) & 1;
    const int cpx  = tid & 63;
    const int cy   = cpx >> 3, cx = cpx & 7;
    const int och2 = (tid >> 6) * 2;           // C-rec state owner pair

    // ---- stage D: thread = (od = t>>7, ddi = (t>>6)&1, px) ----
    const int od  = tid >> 7;
    const int ddi = (tid >> 6) & 1;
    const int dpx = tid & 63;
    const int dy  = dpx >> 3, dxx = dpx & 7;
    const int diy = gy0 + dy, dix = gx0 + dxx;

    // bilinear 2x upsample weights (jax.image.resize "linear")
    const float ay  = ddi ? ((diy == 63) ? 1.f : 0.75f) : ((diy == 0) ? 0.f : 0.25f);
    const float byw = ddi ? ((diy == 63) ? 0.f : 0.25f) : ((diy == 0) ? 1.f : 0.75f);
    const float ax0 = (dix == 0)  ? 0.f : 0.25f;   // dj = 0
    const float bx0 = (dix == 0)  ? 1.f : 0.75f;
    const float ax1 = (dix == 63) ? 1.f : 0.75f;   // dj = 1
    const float bx1 = (dix == 63) ? 0.f : 0.25f;
    const int   didx = (dy + 2 + ddi) * 16 + (dxx + 2);

    // ---- prefetch registers: chunk 0's input ----
    float4 x00 = make_float4(0.f,0.f,0.f,0.f), x01 = x00, x10 = x00, x11 = x00;
    if (avalid) {
        x00 = *(const float4*)(spk + aoff0);
        x01 = *(const float4*)(spk + aoff0 + 4);
        x10 = *(const float4*)(spk + aoff1);
        x11 = *(const float4*)(spk + aoff1 + 4);
    }

#pragma unroll 1
    for (int ck = 0; ck < 25; ++ck) {
        const int t0 = ck * 8;
        const int p  = ck & 1;

        // ================= stage A: psp1 + prefetch next chunk =============
        if (tid < 196) {
            float4 v;
            PSP4(v, x00, aP0); sP1[p][0][0][aidx] = v;
            PSP4(v, x01, aP0); sP1[p][0][1][aidx] = v;
            PSP4(v, x10, aP1); sP1[p][1][0][aidx] = v;
            PSP4(v, x11, aP1); sP1[p][1][1][aidx] = v;
            if (ck < 24 && avalid) {
                x00 = *(const float4*)(spk + aoff0 + t0 + 8);
                x01 = *(const float4*)(spk + aoff0 + t0 + 12);
                x10 = *(const float4*)(spk + aoff1 + t0 + 8);
                x11 = *(const float4*)(spk + aoff1 + t0 + 12);
            }
        }
        __syncthreads();   // b1: sP1[p] ready; prev-chunk C-conv done with sP2

        // ============ stage B-conv: conv1 5x5, all 8 och, one t-half =======
        if (bpx < 100) {
            v2f alo[8], ahi[8];
#pragma unroll
            for (int o = 0; o < 8; ++o) { alo[o] = (v2f)(0.f); ahi[o] = (v2f)(0.f); }
#pragma unroll 1
            for (int c = 0; c < 2; ++c) {
#pragma unroll 1
                for (int ky = 0; ky < 5; ++ky) {
                    const float4* r0 = &sP1[p][c][bh][(by + ky) * 16 + bx];
                    const float*  wrow = wr + (c * 25 + ky * 5) * 8;
#pragma unroll
                    for (int kx = 0; kx < 5; ++kx) {
                        float4 d = r0[kx];
                        v2f dlo = { d.x, d.y }, dhi = { d.z, d.w };
#pragma unroll
                        for (int o = 0; o < 8; ++o) {
                            float wv = wrow[kx * 8 + o];
                            PKFMA(alo[o], ahi[o], wv, dlo, dhi);
                        }
                    }
                }
            }
#pragma unroll
            for (int o = 0; o < 8; ++o)
                sP2[o][bh][bwr] = make_float4(alo[o].x, alo[o].y, ahi[o].x, ahi[o].y);
        }
        __syncthreads();   // b2: acc ready

        // ============ stage B-rec: spike1 + psp2 in-place on sP2 ===========
        if (bpx < 100) {
#pragma unroll
            for (int j = 0; j < 4; ++j) {
                const int o = ochB * 4 + j;
                float4 u0 = sP2[o][0][bwr];
                float4 u1 = sP2[o][1][bwr];
                float4 q0 = spike_psp4(u0, 30.f, DEC1, DEC2, rB[j], qB[j]);
                sP2[o][0][bwr] = q0;
                float4 q1 = spike_psp4(u1, 30.f, DEC1, DEC2, rB[j], qB[j]);
                sP2[o][1][bwr] = q1;
            }
        }
        __syncthreads();   // b3: psp2 ready

        // ============ stage C-conv: conv2 3x3, och quad, one t-half ========
        {
            v2f alo[4], ahi[4];
#pragma unroll
            for (int j = 0; j < 4; ++j) { alo[j] = (v2f)(0.f); ahi[j] = (v2f)(0.f); }
            const float* wC = wr + 400 + cop * 4;
#pragma unroll 1
            for (int c = 0; c < 8; ++c) {
#pragma unroll 1
                for (int ky = 0; ky < 3; ++ky) {
                    const float4* r0 = &sP2[c][ch2][(cy + ky) * 10 + cx];
                    const float*  wrow = wC + (c * 9 + ky * 3) * 8;
#pragma unroll
                    for (int kx = 0; kx < 3; ++kx) {
                        float4 d = r0[kx];
                        v2f dlo = { d.x, d.y }, dhi = { d.z, d.w };
#pragma unroll
                        for (int j = 0; j < 4; ++j) {
                            float wv = wrow[kx * 8 + j];
                            PKFMA(alo[j], ahi[j], wv, dlo, dhi);
                        }
                    }
                }
            }
#pragma unroll
            for (int j = 0; j < 4; ++j)
                sP3[cop * 4 + j][ch2][cpx] =
                    make_float4(alo[j].x, alo[j].y, ahi[j].x, ahi[j].y);
        }
        __syncthreads();   // b4: acc ready

        // ============ stage C-rec: spike2 + psp3 in-place on sP3 ===========
        {
#pragma unroll
            for (int j = 0; j < 2; ++j) {
                const int o = och2 + j;
                float4 u0 = sP3[o][0][cpx];
                float4 u1 = sP3[o][1][cpx];
                float4 q0 = spike_psp4(u0, 50.f, DEC2, DEC3, rC[j], qC[j]);
                sP3[o][0][cpx] = q0;
                float4 q1 = spike_psp4(u1, 50.f, DEC2, DEC3, rC[j], qC[j]);
                sP3[o][1][cpx] = q1;
            }
        }
        __syncthreads();   // b5: psp3 ready

        // ============ stage D: convT 2x2 s2 + psp1 bilinear-up + spike3 ====
        {
#pragma unroll 1
            for (int h = 0; h < 2; ++h) {
                float4 p3[8];
#pragma unroll
                for (int c = 0; c < 8; ++c) p3[c] = sP3[c][h][dpx];
                float4 P0a = sP1[p][od][h][didx];
                float4 P0b = sP1[p][od][h][didx + 1];
                float4 P0c = sP1[p][od][h][didx + 2];
                float4 P1a = sP1[p][od][h][didx + 16];
                float4 P1b = sP1[p][od][h][didx + 17];
                float4 P1c = sP1[p][od][h][didx + 18];
#pragma unroll
                for (int dj = 0; dj < 2; ++dj) {
                    const float ax  = dj ? ax1 : ax0;
                    const float bxw = dj ? bx1 : bx0;
                    v2f tlo = (v2f)(0.f), thi = (v2f)(0.f);
                    const float* wD = wr + 976 + ((od * 2 + ddi) * 2 + dj) * 8;
#pragma unroll
                    for (int c = 0; c < 8; ++c) {
                        float wv = wD[c];
                        v2f dlo = { p3[c].x, p3[c].y }, dhi = { p3[c].z, p3[c].w };
                        PKFMA(tlo, thi, wv, dlo, dhi);
                    }
                    float4 tv = make_float4(tlo.x, tlo.y, thi.x, thi.y);
                    float4 A  = dj ? P0b : P0a;
                    float4 Bv = dj ? P0c : P0b;
                    float4 Cv = dj ? P1b : P1a;
                    float4 Dv = dj ? P1c : P1b;
                    float4 up, u; float ra, rb;
                    ra = __fadd_rn(__fmul_rn(ay, A.x),  __fmul_rn(byw, Cv.x));
                    rb = __fadd_rn(__fmul_rn(ay, Bv.x), __fmul_rn(byw, Dv.x));
                    up.x = __fadd_rn(__fmul_rn(ax, ra), __fmul_rn(bxw, rb));
                    ra = __fadd_rn(__fmul_rn(ay, A.y),  __fmul_rn(byw, Cv.y));
                    rb = __fadd_rn(__fmul_rn(ay, Bv.y), __fmul_rn(byw, Dv.y));
                    up.y = __fadd_rn(__fmul_rn(ax, ra), __fmul_rn(bxw, rb));
                    ra = __fadd_rn(__fmul_rn(ay, A.z),  __fmul_rn(byw, Cv.z));
                    rb = __fadd_rn(__fmul_rn(ay, Bv.z), __fmul_rn(byw, Dv.z));
                    up.z = __fadd_rn(__fmul_rn(ax, ra), __fmul_rn(bxw, rb));
                    ra = __fadd_rn(__fmul_rn(ay, A.w),  __fmul_rn(byw, Cv.w));
                    rb = __fadd_rn(__fmul_rn(ay, Bv.w), __fmul_rn(byw, Dv.w));
                    up.w = __fadd_rn(__fmul_rn(ax, ra), __fmul_rn(bxw, rb));
                    u.x = __fadd_rn(tv.x, up.x);
                    u.y = __fadd_rn(tv.y, up.y);
                    u.z = __fadd_rn(tv.z, up.z);
                    u.w = __fadd_rn(tv.w, up.w);
                    float4 ov = spike4(u, 100.f, DEC3, r3[dj]);
                    float* op = out + ((((b * 2 + od) * 128 + (2 * diy + ddi)) * 128)
                                       + (2 * dix + dj)) * 200 + t0 + h * 4;
                    *(float4*)op = ov;
                }
            }
        }
        // no end barrier: next A writes sP1[p^1]; sP2 safe until next B-conv
        // (separated by b1'); sP3 safe until next C-conv (separated by b3').
    }
}

extern "C" void kernel_launch(void* const* d_in, const int* in_sizes, int n_in,
                              void* d_out, int out_size, void* d_ws, size_t ws_size,
                              hipStream_t stream)
{
    const float* spk = (const float*)d_in[0];
    const float* w1  = (const float*)d_in[1];
    const float* w2  = (const float*)d_in[2];
    const float* wup = (const float*)d_in[3];
    float* outp = (float*)d_out;
    float* wr   = (float*)d_ws;   // 1040 floats of re-laid-out weights

    prep_weights<<<dim3(3), dim3(256), 0, stream>>>(w1, w2, wup, wr);
    snn_fused<<<dim3(512), dim3(256), 0, stream>>>(spk, wr, outp);
}